// Round 5
// baseline (2865.856 us; speedup 1.0000x reference)
//
#include <hip/hip_runtime.h>
#include <math.h>

#define NROWS 131072
#define DIMD  128
#define KCB   1024
#define NLEV  4
#define RB    128
#define ACCEPT_EPS 1.0e-4f   // > 2*delta, delta ~ 3.2e-5 (2*ulp(128) + bf16-split)

typedef __attribute__((ext_vector_type(8))) short short8;
typedef __attribute__((ext_vector_type(4))) float f32x4;

// byte offsets in dynamic LDS
#define OFF_RS    0        // f32 rS[128][132]            67584 B
#define OFF_EH    67584    // bf16 eH[128 cols][128 d]    32768 B
#define OFF_EL    100352   // bf16 eL                     32768 B
#define OFF_CS    133120   // f32 C_S[1024]                4096 B
#define OFF_AS    137216   // f32 A_S[128]                  512 B
#define OFF_KMIN  137728   // int kminS[128]                512 B
#define OFF_DEV   138240   // f32 devS[128]                 512 B
#define OFF_SW    138752   // f32 swS[128]                  512 B
#define OFF_COMM  139264   // f32 commitAcc[128]            512 B
#define OFF_USE   139776   // f32 usageAcc[128]             512 B
#define OFF_BEST  140288   // u64 bestS[128]               1024 B
#define OFF_HARD  141312   // int hardList[128]             512 B
#define OFF_HCNT  141824   // int hardCnt                     4 B
#define LDS_BYTES 141828

__device__ __forceinline__ float expm1_poly(float s) {   // |s|<=0.3, validated R3
    float p = fmaf(s, 1.0f / 5040.0f, 1.0f / 720.0f);
    p = fmaf(s, p, 1.0f / 120.0f);
    p = fmaf(s, p, 1.0f / 24.0f);
    p = fmaf(s, p, 1.0f / 6.0f);
    p = fmaf(s, p, 0.5f);
    p = fmaf(s, p, 1.0f);
    return s * p;
}

// numpy pairwise sumsq (AVX512 path) — validated R3. Do not reassociate.
__device__ __forceinline__ float np_sumsq128(const float* __restrict__ p) {
    float q[16];
    #pragma unroll
    for (int lane = 0; lane < 16; ++lane) {
        float c[8];
        #pragma unroll
        for (int j = 0; j < 8; ++j) { float v = p[16 * j + lane]; c[j] = v * v; }
        float s01 = c[0] + c[1], s23 = c[2] + c[3];
        float s45 = c[4] + c[5], s67 = c[6] + c[7];
        q[lane] = (s01 + s23) + (s45 + s67);
    }
    float t[8];
    #pragma unroll
    for (int j = 0; j < 8; ++j) t[j] = q[j] + q[j + 8];
    float u[4];
    #pragma unroll
    for (int j = 0; j < 4; ++j) u[j] = t[j] + t[j + 4];
    float w0 = u[0] + u[2], w1 = u[1] + u[3];
    return w0 + w1;
}

__device__ __forceinline__ float hi_part(float a) {
    return __uint_as_float(__float_as_uint(a) & 0xFFFF0000u);
}
__device__ __forceinline__ unsigned pack_hi(float a, float b) {   // bf16 trunc pair
    return (__float_as_uint(a) >> 16) | (__float_as_uint(b) & 0xFFFF0000u);
}
__device__ __forceinline__ short8 as_short8(uint4 u) {
    short8 v; __builtin_memcpy(&v, &u, 16); return v;
}

__global__ __launch_bounds__(256, 1)
void rvq_main(const float* __restrict__ x, const float* __restrict__ cb,
              float* __restrict__ out, const float* __restrict__ e2g,
              double* __restrict__ lossAcc)
{
    extern __shared__ char smem[];
    float*  rS       = (float*)(smem + OFF_RS);
    char*   eH       = smem + OFF_EH;
    char*   eL       = smem + OFF_EL;
    float*  C_S      = (float*)(smem + OFF_CS);
    float*  A_S      = (float*)(smem + OFF_AS);
    int*    kminS    = (int*)(smem + OFF_KMIN);
    float*  devS     = (float*)(smem + OFF_DEV);
    float*  swS      = (float*)(smem + OFF_SW);
    float*  commitAcc= (float*)(smem + OFF_COMM);
    float*  usageAcc = (float*)(smem + OFF_USE);
    unsigned long long* bestS = (unsigned long long*)(smem + OFF_BEST);
    int*    hardList = (int*)(smem + OFF_HARD);
    int*    hardCnt  = (int*)(smem + OFF_HCNT);

    const int tid = threadIdx.x;
    const int w   = tid >> 6;          // wave 0..3 -> rows [32w, 32w+32)
    const int l   = tid & 63;
    const int li  = l & 15;            // MFMA: A-row / B-col lane index
    const int lg  = l >> 4;            // MFMA: k-slice group
    const int tx  = tid & 15;          // epilogue mapping (R3)
    const int ty  = tid >> 4;
    const int rowBase = blockIdx.x * RB;

    float4* rS4 = (float4*)rS;
    const float4* x4 = (const float4*)x;
    float4* out4 = (float4*)out;

    // init residual = x
    #pragma unroll
    for (int i = 0; i < 8; ++i) {
        int row = 8 * ty + i;
        size_t n = (size_t)rowBase + row;
        rS4[row * 33 + 2 * tx]     = x4[n * 32 + 2 * tx];
        rS4[row * 33 + 2 * tx + 1] = x4[n * 32 + 2 * tx + 1];
    }
    if (tid < RB) { usageAcc[tid] = 0.0f; commitAcc[tid] = 0.0f; }

    for (int lev = 0; lev < NLEV; ++lev) {
        __syncthreads();   // rS stable from previous level
        #pragma unroll
        for (int j = 0; j < KCB / 256; ++j)
            C_S[tid + j * 256] = e2g[lev * KCB + tid + j * 256];
        if (tid < RB) {
            A_S[tid]  = np_sumsq128(rS + tid * 132);   // np pairwise tree
            bestS[tid] = ~0ULL;
        }
        if (tid == 0) *hardCnt = 0;

        const float* cbL = cb + (size_t)lev * KCB * DIMD;
        const float4* cbL4 = (const float4*)cbL;

        // ---- A fragments (bf16 hi/lo of this wave's 32 rows) in registers ----
        // lane l holds A[row = l&15][k = 32*ks + 8*(l>>4) + 0..7]
        short8 aH[2][4], aL[2][4];
        #pragma unroll
        for (int t = 0; t < 2; ++t) {
            int arow = 32 * w + 16 * t + li;
            #pragma unroll
            for (int ks = 0; ks < 4; ++ks) {
                float4 p = rS4[arow * 33 + 8 * ks + 2 * lg];
                float4 q = rS4[arow * 33 + 8 * ks + 2 * lg + 1];
                uint4 uh, ul;
                uh.x = pack_hi(p.x, p.y); uh.y = pack_hi(p.z, p.w);
                uh.z = pack_hi(q.x, q.y); uh.w = pack_hi(q.z, q.w);
                float l0 = p.x - hi_part(p.x), l1 = p.y - hi_part(p.y);
                float l2 = p.z - hi_part(p.z), l3 = p.w - hi_part(p.w);
                float l4 = q.x - hi_part(q.x), l5 = q.y - hi_part(q.y);
                float l6 = q.z - hi_part(q.z), l7 = q.w - hi_part(q.w);
                ul.x = pack_hi(l0, l1); ul.y = pack_hi(l2, l3);
                ul.z = pack_hi(l4, l5); ul.w = pack_hi(l6, l7);
                aH[t][ks] = as_short8(uh);
                aL[t][ks] = as_short8(ul);
            }
        }
        __syncthreads();   // C_S / A_S / bestS visible

        float Areg[8];
        #pragma unroll
        for (int t = 0; t < 2; ++t)
            #pragma unroll
            for (int r = 0; r < 4; ++r)
                Areg[4 * t + r] = A_S[32 * w + 16 * t + 4 * lg + r];

        float m1[8], m2[8], dev[8], sw[8];
        int   k1[8];
        #pragma unroll
        for (int s = 0; s < 8; ++s) {
            m1[s] = __builtin_inff(); m2[s] = __builtin_inff(); k1[s] = 0;
            dev[s] = 0.f; sw[s] = 0.f;
        }

        // ============ single pass: min/top-2 + softmax stats ============
        for (int g = 0; g < 8; ++g) {
            __syncthreads();           // previous group's reads done
            #pragma unroll
            for (int it = 0; it < 16; ++it) {      // stage 128 cols, bf16 hi/lo
                int f = it * 256 + tid;
                int col = f >> 5, c4 = f & 31;
                float4 v = cbL4[(size_t)(128 * g + col) * 32 + c4];
                unsigned h0 = pack_hi(v.x, v.y), h1 = pack_hi(v.z, v.w);
                float m0 = v.x - hi_part(v.x), n1 = v.y - hi_part(v.y);
                float n2 = v.z - hi_part(v.z), n3 = v.w - hi_part(v.w);
                unsigned o0 = pack_hi(m0, n1), o1 = pack_hi(n2, n3);
                // byte u of col c stored at (c*256+u) ^ ((c&7)<<4)
                int ba = (col * 256 + c4 * 8) ^ ((col & 7) << 4);
                *(uint2*)(eH + ba) = make_uint2(h0, h1);
                *(uint2*)(eL + ba) = make_uint2(o0, o1);
            }
            __syncthreads();
            for (int ct = 0; ct < 8; ++ct) {
                const int colr = 16 * ct + li;
                const int S    = (colr & 7) << 4;
                const int base = colr * 256 + lg * 16;
                short8 bH[4], bL[4];
                #pragma unroll
                for (int ks = 0; ks < 4; ++ks) {
                    // FIX: XOR applied to the FULL byte address (bug in R4)
                    const int ba = (base + 64 * ks) ^ S;
                    bH[ks] = *(const short8*)(eH + ba);
                    bL[ks] = *(const short8*)(eL + ba);
                }
                f32x4 accH0 = {0.f,0.f,0.f,0.f}, accH1 = {0.f,0.f,0.f,0.f};
                f32x4 accA0 = {0.f,0.f,0.f,0.f}, accA1 = {0.f,0.f,0.f,0.f};
                f32x4 accB0 = {0.f,0.f,0.f,0.f}, accB1 = {0.f,0.f,0.f,0.f};
                #pragma unroll
                for (int ks = 0; ks < 4; ++ks) {   // 6 independent chains, depth 4
                    accH0 = __builtin_amdgcn_mfma_f32_16x16x32_bf16(aH[0][ks], bH[ks], accH0, 0, 0, 0);
                    accH1 = __builtin_amdgcn_mfma_f32_16x16x32_bf16(aH[1][ks], bH[ks], accH1, 0, 0, 0);
                    accA0 = __builtin_amdgcn_mfma_f32_16x16x32_bf16(aH[0][ks], bL[ks], accA0, 0, 0, 0);
                    accA1 = __builtin_amdgcn_mfma_f32_16x16x32_bf16(aH[1][ks], bL[ks], accA1, 0, 0, 0);
                    accB0 = __builtin_amdgcn_mfma_f32_16x16x32_bf16(aL[0][ks], bH[ks], accB0, 0, 0, 0);
                    accB1 = __builtin_amdgcn_mfma_f32_16x16x32_bf16(aL[1][ks], bH[ks], accB1, 0, 0, 0);
                }
                const float Cc = C_S[128 * g + colr];
                const int colg = 128 * g + colr;
                #pragma unroll
                for (int t = 0; t < 2; ++t) {
                    #pragma unroll
                    for (int r = 0; r < 4; ++r) {
                        const int s = 4 * t + r;
                        float bh = t ? ((accH1[r] + accA1[r]) + accB1[r])
                                     : ((accH0[r] + accA0[r]) + accB0[r]);
                        float dh = fmaf(-2.0f, bh, Areg[s]) + Cc;
                        if (dh < m1[s])      { m2[s] = m1[s]; m1[s] = dh; k1[s] = colg; }
                        else if (dh < m2[s]) { m2[s] = dh; }
                        float sv = Areg[s] - dh;
                        float em = expm1_poly(sv);
                        dev[s] += em;
                        sw[s]  += sv;
                        sw[s]   = fmaf(sv, em, sw[s]);
                    }
                }
            }
        }

        // merge across the 16 lanes sharing rows (lanes lg*16..lg*16+15)
        #pragma unroll
        for (int s = 0; s < 8; ++s) {
            #pragma unroll
            for (int m = 8; m >= 1; m >>= 1) {
                float om1 = __shfl_xor(m1[s], m);
                float om2 = __shfl_xor(m2[s], m);
                int   ok1 = __shfl_xor(k1[s], m);
                float nm1, nm2; int nk1;
                if (om1 < m1[s])      { nm1 = om1;   nk1 = ok1;   nm2 = fminf(om2, m1[s]); }
                else if (om1 > m1[s]) { nm1 = m1[s]; nk1 = k1[s]; nm2 = fminf(m2[s], om1); }
                else                  { nm1 = m1[s]; nk1 = min(k1[s], ok1); nm2 = m1[s]; }
                m1[s] = nm1; m2[s] = nm2; k1[s] = nk1;
                dev[s] += __shfl_xor(dev[s], m);
                sw[s]  += __shfl_xor(sw[s], m);
            }
        }
        if (li == 0) {
            #pragma unroll
            for (int t = 0; t < 2; ++t)
                #pragma unroll
                for (int r = 0; r < 4; ++r) {
                    const int s = 4 * t + r;
                    const int row = 32 * w + 16 * t + 4 * lg + r;
                    kminS[row] = k1[s];
                    devS[row]  = dev[s];
                    swS[row]   = sw[s];
                    if (!(m2[s] - m1[s] > ACCEPT_EPS)) {   // hard row
                        int p = atomicAdd(hardCnt, 1);
                        hardList[p] = row;
                    }
                }
        }
        __syncthreads();   // kminS/devS/swS/hardList complete

        // hard rows: exact fp32-replica scan over all 1024 k (R3-proven chain)
        const int nh = *hardCnt;
        for (int h = 0; h < nh; ++h) {
            const int row = hardList[h];
            const float* rrow = rS + row * 132;
            const float Ar = A_S[row];
            unsigned long long best = ~0ULL;
            for (int kk = tid; kk < KCB; kk += 256) {
                const float4* ep4 = (const float4*)(cbL + (size_t)kk * DIMD);
                float b = 0.f;
                #pragma unroll 8
                for (int c4 = 0; c4 < 32; ++c4) {   // sequential ascending-d FMA
                    float4 ev = ep4[c4];
                    const float* rp = rrow + 4 * c4;
                    b = fmaf(rp[0], ev.x, b);
                    b = fmaf(rp[1], ev.y, b);
                    b = fmaf(rp[2], ev.z, b);
                    b = fmaf(rp[3], ev.w, b);
                }
                float m2b = 2.0f * b;
                float t1  = Ar - m2b;
                float d32 = t1 + C_S[kk];           // >0 always (~128)
                unsigned long long pk =
                    ((unsigned long long)__float_as_uint(d32) << 32) | (unsigned)kk;
                if (pk < best) best = pk;
            }
            #pragma unroll
            for (int m = 32; m >= 1; m >>= 1) {
                unsigned long long o = __shfl_xor(best, m);
                if (o < best) best = o;
            }
            if ((tid & 63) == 0) atomicMin(&bestS[row], best);
        }
        __syncthreads();   // bestS final

        // ---- epilogue (R3 validated): residual chain, codes, losses, out ----
        #pragma unroll
        for (int i = 0; i < 8; ++i) {
            const int row = 8 * ty + i;
            const size_t n = (size_t)rowBase + row;
            unsigned long long bs = bestS[row];
            const int bestk = (bs != ~0ULL) ? (int)(bs & 1023ULL) : kminS[row];

            const float4* q4p = (const float4*)(cbL + (size_t)bestk * DIMD);
            float4 qa = q4p[2 * tx], qb = q4p[2 * tx + 1];
            float4 ra = rS4[row * 33 + 2 * tx], rb = rS4[row * 33 + 2 * tx + 1];

            float nr0 = ra.x - qa.x, nr1 = ra.y - qa.y;
            float nr2 = ra.z - qa.z, nr3 = ra.w - qa.w;
            float nr4 = rb.x - qb.x, nr5 = rb.y - qb.y;
            float nr6 = rb.z - qb.z, nr7 = rb.w - qb.w;

            double cpart = 0.0;
            cpart += (double)(nr0 * nr0); cpart += (double)(nr1 * nr1);
            cpart += (double)(nr2 * nr2); cpart += (double)(nr3 * nr3);
            cpart += (double)(nr4 * nr4); cpart += (double)(nr5 * nr5);
            cpart += (double)(nr6 * nr6); cpart += (double)(nr7 * nr7);
            #pragma unroll
            for (int m = 8; m >= 1; m >>= 1) cpart += __shfl_xor(cpart, m);

            rS4[row * 33 + 2 * tx]     = make_float4(nr0, nr1, nr2, nr3);
            rS4[row * 33 + 2 * tx + 1] = make_float4(nr4, nr5, nr6, nr7);

            if (tx == 0) {
                out[(size_t)NROWS * DIMD + n * NLEV + lev] = (float)bestk;
                commitAcc[row] += (float)cpart;
                usageAcc[row]  += swS[row] / (1024.0f + devS[row])
                                - log1pf(devS[row] * (1.0f / 1024.0f));
            }
            if (lev == NLEV - 1) {
                float4 xa = x4[n * 32 + 2 * tx];
                float4 xb = x4[n * 32 + 2 * tx + 1];
                out4[n * 32 + 2 * tx] = make_float4(
                    xa.x - nr0, xa.y - nr1, xa.z - nr2, xa.w - nr3);
                out4[n * 32 + 2 * tx + 1] = make_float4(
                    xb.x - nr4, xb.y - nr5, xb.z - nr6, xb.w - nr7);
            }
        }
    }

    __syncthreads();
    float u = 0.f, cm = 0.f;
    if (tid < RB) { u = usageAcc[tid]; cm = commitAcc[tid]; }
    #pragma unroll
    for (int m = 32; m >= 1; m >>= 1) { u += __shfl_xor(u, m); cm += __shfl_xor(cm, m); }
    if ((tid & 63) == 0) {
        atomicAdd(&lossAcc[0], (double)cm);
        atomicAdd(&lossAcc[1], (double)u);
    }
}

__global__ void rvq_prep(const float* __restrict__ cb, float* __restrict__ e2g,
                         double* __restrict__ lossAcc)
{
    int k = blockIdx.x * blockDim.x + threadIdx.x;   // 0..4095
    if (k == 0) { lossAcc[0] = 0.0; lossAcc[1] = 0.0; }
    if (k < NLEV * KCB) {
        e2g[k] = np_sumsq128(cb + (size_t)k * DIMD);
    }
}

__global__ void rvq_fin(const double* __restrict__ lossAcc, float* __restrict__ out)
{
    out[(size_t)NROWS * DIMD + (size_t)NROWS * NLEV] =
        (float)(lossAcc[0] * (1.25 / ((double)NROWS * (double)DIMD)));
    out[(size_t)NROWS * DIMD + (size_t)NROWS * NLEV + 1] =
        (float)(lossAcc[1] / (double)NROWS);
}

extern "C" void kernel_launch(void* const* d_in, const int* in_sizes, int n_in,
                              void* d_out, int out_size, void* d_ws, size_t ws_size,
                              hipStream_t stream)
{
    const float* x  = (const float*)d_in[0];
    const float* cb = (const float*)d_in[1];
    float* out = (float*)d_out;
    double* lossAcc = (double*)d_ws;                 // [0]=commit, [1]=usage
    float* e2g = (float*)((char*)d_ws + 16);         // 4*1024 floats

    (void)hipFuncSetAttribute((const void*)rvq_main,
                              hipFuncAttributeMaxDynamicSharedMemorySize, LDS_BYTES);

    rvq_prep<<<dim3((NLEV * KCB) / 256), dim3(256), 0, stream>>>(cb, e2g, lossAcc);
    rvq_main<<<dim3(NROWS / RB), dim3(256), LDS_BYTES, stream>>>(x, cb, out, e2g, lossAcc);
    rvq_fin<<<dim3(1), dim3(1), 0, stream>>>(lossAcc, out);
}

// Round 6
// 1464.494 us; speedup vs baseline: 1.9569x; 1.9569x over previous
//
#include <hip/hip_runtime.h>
#include <math.h>

#define NROWS 131072
#define DIMD  128
#define KCB   1024
#define NLEV  4
#define RB    32                 // rows per block (1 wave)
#define ACCEPT_EPS 1.0e-4f       // gap accept threshold; > 2*delta (delta~1.6e-5)

typedef __attribute__((ext_vector_type(8))) short short8;
typedef __attribute__((ext_vector_type(4))) float f32x4;

// d_ws layout (requires ws_size >= ~2.1 MB):
//   [0..16)          double lossAcc[2]
//   [16..16400)      f32 e2g[4096]           (np-tree sum(e^2), validated R3)
//   [16400..)        bf16 hiT: 4 lev x 16384 uint4 (256 KB/lev)  = 1 MB
//   [+1MB..)         bf16 loT: same                              = 1 MB
#define WS_E2G   16
#define WS_HIT   16400
#define WS_LOT   (16400 + 1048576)

__device__ __forceinline__ float expm1_poly(float s) {   // |s|<=0.32, validated R3/R5
    float p = fmaf(s, 1.0f / 5040.0f, 1.0f / 720.0f);
    p = fmaf(s, p, 1.0f / 120.0f);
    p = fmaf(s, p, 1.0f / 24.0f);
    p = fmaf(s, p, 1.0f / 6.0f);
    p = fmaf(s, p, 0.5f);
    p = fmaf(s, p, 1.0f);
    return s * p;
}

// numpy pairwise sumsq (AVX512 path) — validated R3/R5. Do not reassociate.
__device__ __forceinline__ float np_sumsq128(const float* __restrict__ p) {
    float q[16];
    #pragma unroll
    for (int lane = 0; lane < 16; ++lane) {
        float c[8];
        #pragma unroll
        for (int j = 0; j < 8; ++j) { float v = p[16 * j + lane]; c[j] = v * v; }
        float s01 = c[0] + c[1], s23 = c[2] + c[3];
        float s45 = c[4] + c[5], s67 = c[6] + c[7];
        q[lane] = (s01 + s23) + (s45 + s67);
    }
    float t[8];
    #pragma unroll
    for (int j = 0; j < 8; ++j) t[j] = q[j] + q[j + 8];
    float u[4];
    #pragma unroll
    for (int j = 0; j < 4; ++j) u[j] = t[j] + t[j + 4];
    float w0 = u[0] + u[2], w1 = u[1] + u[3];
    return w0 + w1;
}

__device__ __forceinline__ short8 as_short8(uint4 u) {
    short8 v; __builtin_memcpy(&v, &u, 16); return v;
}

__global__ __launch_bounds__(64, 2)
void rvq_main(const float* __restrict__ x, const float* __restrict__ cb,
              float* __restrict__ out, const float* __restrict__ e2g,
              const uint4* __restrict__ hiT, const uint4* __restrict__ loT,
              double* __restrict__ lossAcc)
{
    __shared__ float rS[RB * 132];                 // f32 residual chain, 16B-aligned rows
    __shared__ unsigned long long bestS[RB];
    __shared__ float A_S[RB];
    __shared__ int   kminS[RB];
    __shared__ float devS[RB], swS[RB];
    __shared__ float commitS[RB], usageS[RB];
    __shared__ int   hardList[RB];
    __shared__ int   hardCnt;

    const int tid = threadIdx.x;                   // 0..63 (one wave)
    const int li  = tid & 15;                      // MFMA col-lane / epilogue dim-lane
    const int lg  = tid >> 4;                      // 0..3: MFMA k-slice / epilogue row-group
    const int rowBase = blockIdx.x * RB;

    float4* rS4 = (float4*)rS;
    const float4* x4 = (const float4*)x;
    float4* out4 = (float4*)out;

    // init residual = x  (rows 8*lg + 0..7, dims 8*li..)
    #pragma unroll
    for (int i = 0; i < 8; ++i) {
        int row = 8 * lg + i;
        size_t n = (size_t)rowBase + row;
        rS4[row * 33 + 2 * li]     = x4[n * 32 + 2 * li];
        rS4[row * 33 + 2 * li + 1] = x4[n * 32 + 2 * li + 1];
    }
    if (tid < RB) { commitS[tid] = 0.0f; usageS[tid] = 0.0f; }

    for (int lev = 0; lev < NLEV; ++lev) {
        __syncthreads();
        if (tid < RB) {
            A_S[tid]  = np_sumsq128(rS + tid * 132);   // np pairwise tree (ref-exact)
            bestS[tid] = ~0ULL;
        }
        if (tid == 0) hardCnt = 0;

        const float* cbL  = cb  + (size_t)lev * KCB * DIMD;
        const float* e2gL = e2g + (size_t)lev * KCB;
        const uint4* hT = hiT + (size_t)lev * 16384;   // 64cg * 4ks * 64lane
        const uint4* lT = loT + (size_t)lev * 16384;

        // A fragments (bf16 hi/lo of 32 rows): lane holds A[row=16t+li][k=32ks+8lg+e]
        short8 aH[2][4], aL[2][4];
        #pragma unroll
        for (int t = 0; t < 2; ++t) {
            int arow = 16 * t + li;
            #pragma unroll
            for (int ks = 0; ks < 4; ++ks) {
                float4 p = rS4[arow * 33 + 8 * ks + 2 * lg];
                float4 q = rS4[arow * 33 + 8 * ks + 2 * lg + 1];
                uint4 uh, ul;
                float pv[8] = {p.x, p.y, p.z, p.w, q.x, q.y, q.z, q.w};
                unsigned hb[8]; float lv[8];
                #pragma unroll
                for (int e = 0; e < 8; ++e) {
                    unsigned b = __float_as_uint(pv[e]);
                    hb[e] = b & 0xFFFF0000u;
                    lv[e] = pv[e] - __uint_as_float(hb[e]);
                }
                uh.x = (hb[0] >> 16) | hb[1]; uh.y = (hb[2] >> 16) | hb[3];
                uh.z = (hb[4] >> 16) | hb[5]; uh.w = (hb[6] >> 16) | hb[7];
                ul.x = (__float_as_uint(lv[0]) >> 16) | (__float_as_uint(lv[1]) & 0xFFFF0000u);
                ul.y = (__float_as_uint(lv[2]) >> 16) | (__float_as_uint(lv[3]) & 0xFFFF0000u);
                ul.z = (__float_as_uint(lv[4]) >> 16) | (__float_as_uint(lv[5]) & 0xFFFF0000u);
                ul.w = (__float_as_uint(lv[6]) >> 16) | (__float_as_uint(lv[7]) & 0xFFFF0000u);
                aH[t][ks] = as_short8(uh);
                aL[t][ks] = as_short8(ul);
            }
        }

        float m1[8], m2[8], dev[8], swv[8];
        int   k1[8];
        #pragma unroll
        for (int s = 0; s < 8; ++s) {
            m1[s] = -__builtin_inff(); m2[s] = -__builtin_inff(); k1[s] = 0;
            dev[s] = 0.f; swv[s] = 0.f;
        }

        // per-cg compute: 24 MFMA + 8 score epilogues (sv = 2r·e − ||e||²; max-sv)
        auto compute_cg = [&](const uint4 (&hf)[4], const uint4 (&lf)[4], int cg) {
            short8 bH[4], bL[4];
            #pragma unroll
            for (int ks = 0; ks < 4; ++ks) { bH[ks] = as_short8(hf[ks]); bL[ks] = as_short8(lf[ks]); }
            f32x4 accH0 = {0.f,0.f,0.f,0.f}, accH1 = {0.f,0.f,0.f,0.f};
            f32x4 accA0 = {0.f,0.f,0.f,0.f}, accA1 = {0.f,0.f,0.f,0.f};
            f32x4 accB0 = {0.f,0.f,0.f,0.f}, accB1 = {0.f,0.f,0.f,0.f};
            #pragma unroll
            for (int ks = 0; ks < 4; ++ks) {       // 6 independent chains, depth 4
                accH0 = __builtin_amdgcn_mfma_f32_16x16x32_bf16(aH[0][ks], bH[ks], accH0, 0, 0, 0);
                accH1 = __builtin_amdgcn_mfma_f32_16x16x32_bf16(aH[1][ks], bH[ks], accH1, 0, 0, 0);
                accA0 = __builtin_amdgcn_mfma_f32_16x16x32_bf16(aH[0][ks], bL[ks], accA0, 0, 0, 0);
                accA1 = __builtin_amdgcn_mfma_f32_16x16x32_bf16(aH[1][ks], bL[ks], accA1, 0, 0, 0);
                accB0 = __builtin_amdgcn_mfma_f32_16x16x32_bf16(aL[0][ks], bH[ks], accB0, 0, 0, 0);
                accB1 = __builtin_amdgcn_mfma_f32_16x16x32_bf16(aL[1][ks], bH[ks], accB1, 0, 0, 0);
            }
            const float Cc = e2gL[cg * 16 + li];
            const int colg = cg * 16 + li;
            #pragma unroll
            for (int t = 0; t < 2; ++t) {
                #pragma unroll
                for (int r = 0; r < 4; ++r) {
                    const int s = 4 * t + r;
                    float b2 = t ? ((accH1[r] + accA1[r]) + accB1[r])
                                 : ((accH0[r] + accA0[r]) + accB0[r]);
                    float sv = b2 - Cc;            // ~ A - d32, err <= ~1.6e-5
                    if (sv > m1[s])      { m2[s] = m1[s]; m1[s] = sv; k1[s] = colg; }
                    else if (sv > m2[s]) { m2[s] = sv; }
                    float em = expm1_poly(sv);
                    dev[s] += em;
                    swv[s] += sv;
                    swv[s]  = fmaf(sv, em, swv[s]);
                }
            }
        };

        // sweep 64 col-groups, register double-buffered global frag loads
        uint4 h0[4], l0[4], h1[4], l1[4];
        #pragma unroll
        for (int ks = 0; ks < 4; ++ks) { h0[ks] = hT[ks * 64 + tid]; l0[ks] = lT[ks * 64 + tid]; }
        for (int cg = 0; cg < 64; cg += 2) {
            #pragma unroll
            for (int ks = 0; ks < 4; ++ks) {
                h1[ks] = hT[(cg + 1) * 256 + ks * 64 + tid];
                l1[ks] = lT[(cg + 1) * 256 + ks * 64 + tid];
            }
            compute_cg(h0, l0, cg);
            if (cg + 2 < 64) {
                #pragma unroll
                for (int ks = 0; ks < 4; ++ks) {
                    h0[ks] = hT[(cg + 2) * 256 + ks * 64 + tid];
                    l0[ks] = lT[(cg + 2) * 256 + ks * 64 + tid];
                }
            }
            compute_cg(h1, l1, cg + 1);
        }

        // merge across the 16 lanes sharing rows (xor 8..1 keeps lg fixed)
        #pragma unroll
        for (int s = 0; s < 8; ++s) {
            #pragma unroll
            for (int m = 8; m >= 1; m >>= 1) {
                float om1 = __shfl_xor(m1[s], m);
                float om2 = __shfl_xor(m2[s], m);
                int   ok1 = __shfl_xor(k1[s], m);
                float nm1, nm2; int nk1;
                if (om1 > m1[s])      { nm1 = om1;   nk1 = ok1;   nm2 = fmaxf(om2, m1[s]); }
                else if (om1 < m1[s]) { nm1 = m1[s]; nk1 = k1[s]; nm2 = fmaxf(m2[s], om1); }
                else                  { nm1 = m1[s]; nk1 = min(k1[s], ok1); nm2 = m1[s]; }
                m1[s] = nm1; m2[s] = nm2; k1[s] = nk1;
                dev[s] += __shfl_xor(dev[s], m);
                swv[s] += __shfl_xor(swv[s], m);
            }
        }
        if (li == 0) {
            #pragma unroll
            for (int t = 0; t < 2; ++t)
                #pragma unroll
                for (int r = 0; r < 4; ++r) {
                    const int s = 4 * t + r;
                    const int row = 16 * t + 4 * lg + r;
                    kminS[row] = k1[s];
                    devS[row]  = dev[s];
                    swS[row]   = swv[s];
                    if (!(m1[s] - m2[s] > ACCEPT_EPS)) {   // hard row
                        int p = atomicAdd(&hardCnt, 1);
                        hardList[p] = row;
                    }
                }
        }
        __syncthreads();

        // hard rows: exact fp32-replica scan over all 1024 k (R3-proven chain)
        const int nh = hardCnt;
        for (int h = 0; h < nh; ++h) {
            const int row = hardList[h];
            const float4* rrow4 = (const float4*)(rS + row * 132);   // broadcast reads
            const float Ar = A_S[row];
            unsigned long long best = ~0ULL;
            for (int kk = tid; kk < KCB; kk += 64) {
                const float4* ep4 = (const float4*)(cbL + (size_t)kk * DIMD);
                float b = 0.f;
                #pragma unroll 8
                for (int c4 = 0; c4 < 32; ++c4) {   // sequential ascending-d FMA
                    float4 ev = ep4[c4];
                    float4 rv = rrow4[c4];
                    b = fmaf(rv.x, ev.x, b);
                    b = fmaf(rv.y, ev.y, b);
                    b = fmaf(rv.z, ev.z, b);
                    b = fmaf(rv.w, ev.w, b);
                }
                float m2b = 2.0f * b;
                float t1  = Ar - m2b;
                float d32 = t1 + e2gL[kk];          // > 0 always (~128)
                unsigned long long pk =
                    ((unsigned long long)__float_as_uint(d32) << 32) | (unsigned)kk;
                if (pk < best) best = pk;
            }
            #pragma unroll
            for (int m = 32; m >= 1; m >>= 1) {
                unsigned long long o = __shfl_xor(best, m);
                if (o < best) best = o;
            }
            if (tid == 0) bestS[row] = best;
        }
        __syncthreads();

        // epilogue (R3/R5 validated): residual chain, codes, losses, out
        #pragma unroll
        for (int i = 0; i < 8; ++i) {
            const int row = 8 * lg + i;
            const size_t n = (size_t)rowBase + row;
            unsigned long long bs = bestS[row];
            const int bestk = (bs != ~0ULL) ? (int)(bs & 1023ULL) : kminS[row];

            const float4* q4p = (const float4*)(cbL + (size_t)bestk * DIMD);
            float4 qa = q4p[2 * li], qb = q4p[2 * li + 1];
            float4 ra = rS4[row * 33 + 2 * li], rb = rS4[row * 33 + 2 * li + 1];

            float nr0 = ra.x - qa.x, nr1 = ra.y - qa.y;
            float nr2 = ra.z - qa.z, nr3 = ra.w - qa.w;
            float nr4 = rb.x - qb.x, nr5 = rb.y - qb.y;
            float nr6 = rb.z - qb.z, nr7 = rb.w - qb.w;

            double cpart = 0.0;
            cpart += (double)(nr0 * nr0); cpart += (double)(nr1 * nr1);
            cpart += (double)(nr2 * nr2); cpart += (double)(nr3 * nr3);
            cpart += (double)(nr4 * nr4); cpart += (double)(nr5 * nr5);
            cpart += (double)(nr6 * nr6); cpart += (double)(nr7 * nr7);
            #pragma unroll
            for (int m = 8; m >= 1; m >>= 1) cpart += __shfl_xor(cpart, m);

            rS4[row * 33 + 2 * li]     = make_float4(nr0, nr1, nr2, nr3);
            rS4[row * 33 + 2 * li + 1] = make_float4(nr4, nr5, nr6, nr7);

            if (li == 0) {
                out[(size_t)NROWS * DIMD + n * NLEV + lev] = (float)bestk;
                commitS[row] += (float)cpart;
                usageS[row]  += swS[row] / (1024.0f + devS[row])
                              - log1pf(devS[row] * (1.0f / 1024.0f));
            }
            if (lev == NLEV - 1) {
                float4 xa = x4[n * 32 + 2 * li];
                float4 xb = x4[n * 32 + 2 * li + 1];
                out4[n * 32 + 2 * li] = make_float4(
                    xa.x - nr0, xa.y - nr1, xa.z - nr2, xa.w - nr3);
                out4[n * 32 + 2 * li + 1] = make_float4(
                    xb.x - nr4, xb.y - nr5, xb.z - nr6, xb.w - nr7);
            }
        }
    }

    __syncthreads();
    float u = 0.f, cm = 0.f;
    if (tid < RB) { u = usageS[tid]; cm = commitS[tid]; }
    #pragma unroll
    for (int m = 32; m >= 1; m >>= 1) { u += __shfl_xor(u, m); cm += __shfl_xor(cm, m); }
    if (tid == 0) {
        atomicAdd(&lossAcc[0], (double)cm);
        atomicAdd(&lossAcc[1], (double)u);
    }
}

// prep: loss reset, C = np_sumsq (ref-exact), and bf16 hi/lo frag tables (pre-scaled x2)
__global__ void rvq_prep(const float* __restrict__ cb, float* __restrict__ e2g,
                         uint4* __restrict__ hiT, uint4* __restrict__ loT,
                         double* __restrict__ lossAcc)
{
    int idx = blockIdx.x * 256 + threadIdx.x;      // 0..65535
    if (idx == 0) { lossAcc[0] = 0.0; lossAcc[1] = 0.0; }
    if (idx < NLEV * KCB)
        e2g[idx] = np_sumsq128(cb + (size_t)idx * DIMD);

    // (lev, cg, ks, lane) <- idx, lane fastest
    int lev = idx >> 14, rem = idx & 16383;
    int cg = rem >> 8, ks = (rem >> 6) & 3, lane = rem & 63;
    int col = cg * 16 + (lane & 15);
    int k0  = ks * 32 + (lane >> 4) * 8;
    const float* src = cb + ((size_t)lev * KCB + col) * DIMD + k0;
    unsigned hb[8], lb[8];
    #pragma unroll
    for (int e = 0; e < 8; ++e) {
        float w = 2.0f * src[e];                   // exact scale
        unsigned b = __float_as_uint(w);
        hb[e] = b >> 16;                           // trunc bf16 of 2e
        float lv = w - __uint_as_float(b & 0xFFFF0000u);   // exact
        lb[e] = __float_as_uint(lv) >> 16;         // trunc bf16 of residual
    }
    uint4 hp, lp;
    hp.x = hb[0] | (hb[1] << 16); hp.y = hb[2] | (hb[3] << 16);
    hp.z = hb[4] | (hb[5] << 16); hp.w = hb[6] | (hb[7] << 16);
    lp.x = lb[0] | (lb[1] << 16); lp.y = lb[2] | (lb[3] << 16);
    lp.z = lb[4] | (lb[5] << 16); lp.w = lb[6] | (lb[7] << 16);
    hiT[idx] = hp;
    loT[idx] = lp;
}

__global__ void rvq_fin(const double* __restrict__ lossAcc, float* __restrict__ out)
{
    out[(size_t)NROWS * DIMD + (size_t)NROWS * NLEV] =
        (float)(lossAcc[0] * (1.25 / ((double)NROWS * (double)DIMD)));
    out[(size_t)NROWS * DIMD + (size_t)NROWS * NLEV + 1] =
        (float)(lossAcc[1] / (double)NROWS);
}

extern "C" void kernel_launch(void* const* d_in, const int* in_sizes, int n_in,
                              void* d_out, int out_size, void* d_ws, size_t ws_size,
                              hipStream_t stream)
{
    const float* x  = (const float*)d_in[0];
    const float* cb = (const float*)d_in[1];
    float* out = (float*)d_out;
    double* lossAcc = (double*)d_ws;
    float* e2g = (float*)((char*)d_ws + WS_E2G);
    uint4* hiT = (uint4*)((char*)d_ws + WS_HIT);
    uint4* loT = (uint4*)((char*)d_ws + WS_LOT);

    rvq_prep<<<dim3(256), dim3(256), 0, stream>>>(cb, e2g, hiT, loT, lossAcc);
    rvq_main<<<dim3(NROWS / RB), dim3(64), 0, stream>>>(x, cb, out, e2g, hiT, loT, lossAcc);
    rvq_fin<<<dim3(1), dim3(1), 0, stream>>>(lossAcc, out);
}